// Round 8
// baseline (183.917 us; speedup 1.0000x reference)
//
#include <hip/hip_runtime.h>
#include <hip/hip_bf16.h>

#define BATCH 2
#define SEQL 2048
#define NH 16
#define DH 64
#define DM 1024
#define LDK 72   // attn P-tile LDS row stride (bf16): 144B rows -> 2-way (free)
// Q pre-scale folded into qkv_gemm epilogue: 1/sqrt(64) * log2(e)
#define QSCALE 0.1803368801111244f

typedef __hip_bfloat16 bf16;
typedef __attribute__((ext_vector_type(8)))  short bf16x8;
typedef __attribute__((ext_vector_type(4)))  float f32x4;

__device__ __forceinline__ void gl_lds16(const void* g, void* l) {
    __builtin_amdgcn_global_load_lds(
        (const __attribute__((address_space(1))) unsigned int*)g,
        (__attribute__((address_space(3))) unsigned int*)l, 16, 0, 0);
}

// ---------------------------------------------------------------------------
// Prep (fused): z<4 -> weight transpose to bf16 Bt[n][k]; z==4 -> x fp32->bf16
// (grid-stride). grid (16,16,5), block 256.
// ---------------------------------------------------------------------------
__global__ __launch_bounds__(256) void prep_kernel(
    const float* __restrict__ x,
    const float* __restrict__ Wq, const float* __restrict__ Wk,
    const float* __restrict__ Wv, const float* __restrict__ Wo,
    bf16* __restrict__ Wt, bf16* __restrict__ xb)
{
    const int zi = blockIdx.z;
    if (zi == 4) {
        const int bid = blockIdx.y * 16 + blockIdx.x;
        const size_t base = ((size_t)bid * 256 + threadIdx.x) * 4;
        #pragma unroll
        for (int it = 0; it < 16; ++it) {
            const size_t i = base + (size_t)it * 262144;
            const float4 v = *(const float4*)(x + i);
            bf16 o[4];
            o[0] = __float2bfloat16(v.x); o[1] = __float2bfloat16(v.y);
            o[2] = __float2bfloat16(v.z); o[3] = __float2bfloat16(v.w);
            *(uint2*)(xb + i) = *(const uint2*)o;
        }
        return;
    }

    __shared__ float ts[64][65];
    const float* src = (zi == 0) ? Wq : (zi == 1) ? Wk : (zi == 2) ? Wv : Wo;
    bf16* dst = Wt + (size_t)zi * DM * DM;
    const int row0 = blockIdx.y * 64;
    const int col0 = blockIdx.x * 64;
    const int tx = threadIdx.x & 63;
    const int ty = threadIdx.x >> 6;

    if (zi < 3) {
        const int h = col0 >> 6;
        #pragma unroll
        for (int i = 0; i < 16; ++i) {
            const int r = ty + 4 * i;
            ts[r][tx] = src[h * (DM * DH) + (row0 + r) * DH + tx];
        }
    } else {
        #pragma unroll
        for (int i = 0; i < 16; ++i) {
            const int r = ty + 4 * i;
            ts[r][tx] = src[(size_t)(row0 + r) * DM + col0 + tx];
        }
    }
    __syncthreads();
    #pragma unroll
    for (int i = 0; i < 16; ++i) {
        const int rr = ty + 4 * i;
        dst[(size_t)(col0 + rr) * DM + row0 + tx] = __float2bfloat16(ts[tx][rr]);
    }
}

// ---------------------------------------------------------------------------
// QKV GEMM v3 + XCD-chunked block swizzle: the 8 bn-blocks sharing an A-panel
// now land on one XCD (each XCD owns 4 contiguous bm panels + the full B
// slice, ~3MB < 4MB L2). Kernel body unchanged. grid (8, 32, 3), block 256.
// ---------------------------------------------------------------------------
__global__ __launch_bounds__(256) void qkv_gemm(
    const bf16* __restrict__ xb, const bf16* __restrict__ Wt,
    const float* __restrict__ bq, const float* __restrict__ bk, const float* __restrict__ bv,
    bf16* __restrict__ qkv)
{
    __shared__ __align__(16) bf16 As[2][128 * 32];
    __shared__ __align__(16) bf16 Bs[2][128 * 32];

    const int t = threadIdx.x;
    const int lane = t & 63, w = t >> 6;
    const int ml = lane & 15, quad = lane >> 4;
    const int wr = w >> 1, wc = w & 1;
    // XCD-chunked swizzle: bid0 in [0,256); XCD x owns L in [32x, 32x+32)
    // -> bm in [4x, 4x+4) contiguous (A-panels L2-resident per XCD).
    const int bid0 = blockIdx.y * 8 + blockIdx.x;
    const int L = (bid0 & 7) * 32 + (bid0 >> 3);
    const int bn = L & 7, bm = L >> 3;
    const int which = blockIdx.z;

    const bf16* A0 = xb + (size_t)(bm * 128) * DM;
    const bf16* B0 = Wt + (size_t)which * DM * DM + (size_t)(bn * 128) * DM;
    const float* bias = (which == 0) ? bq : (which == 1) ? bk : bv;
    bf16* outb = qkv + (size_t)which * (BATCH * SEQL * NH * DH);
    const float oscale = (which == 0) ? QSCALE : 1.0f;

    f32x4 acc[4][4];
    #pragma unroll
    for (int i = 0; i < 4; ++i)
        #pragma unroll
        for (int j = 0; j < 4; ++j) acc[i][j] = (f32x4){0.f, 0.f, 0.f, 0.f};

    const int r0 = t >> 2, c0 = (t & 3) * 8;
    const int f1 = t + 256;
    const int r1 = f1 >> 2, c1 = (f1 & 3) * 8;

    for (int kt = 0; kt < DM / 64; ++kt) {
        const int k0 = kt * 64;
        __syncthreads();
        #pragma unroll
        for (int half = 0; half < 2; ++half) {
            const int kh = k0 + half * 32;
            gl_lds16(A0 + (size_t)r0 * DM + kh + c0, &As[half][t * 8]);
            gl_lds16(A0 + (size_t)r1 * DM + kh + c1, &As[half][f1 * 8]);
            gl_lds16(B0 + (size_t)r0 * DM + kh + c0, &Bs[half][t * 8]);
            gl_lds16(B0 + (size_t)r1 * DM + kh + c1, &Bs[half][f1 * 8]);
        }
        __syncthreads();
        #pragma unroll
        for (int half = 0; half < 2; ++half) {
            bf16x8 af[4], bfr[4];
            #pragma unroll
            for (int i = 0; i < 4; ++i)
                af[i] = *(const bf16x8*)&As[half][(wr * 64 + i * 16 + ml) * 32 + quad * 8];
            #pragma unroll
            for (int j = 0; j < 4; ++j)
                bfr[j] = *(const bf16x8*)&Bs[half][(wc * 64 + j * 16 + ml) * 32 + quad * 8];
            #pragma unroll
            for (int i = 0; i < 4; ++i)
                #pragma unroll
                for (int j = 0; j < 4; ++j)
                    acc[i][j] = __builtin_amdgcn_mfma_f32_16x16x32_bf16(af[i], bfr[j], acc[i][j], 0, 0, 0);
        }
    }

    float bb[4];
    #pragma unroll
    for (int j = 0; j < 4; ++j) bb[j] = bias[bn * 128 + wc * 64 + j * 16 + ml];

    if (which == 2) {
        #pragma unroll
        for (int i = 0; i < 4; ++i) {
            const int row0v = bm * 128 + wr * 64 + i * 16 + quad * 4;
            const int b = row0v >> 11;
            const int s0 = row0v & (SEQL - 1);
            #pragma unroll
            for (int j = 0; j < 4; ++j) {
                const int col = bn * 128 + wc * 64 + j * 16 + ml;
                const int h = col >> 6, d = col & 63;
                bf16 tmp[4];
                #pragma unroll
                for (int rg = 0; rg < 4; ++rg)
                    tmp[rg] = __float2bfloat16(acc[i][j][rg] + bb[j]);
                *(uint2*)&outb[(((size_t)(b * NH + h)) * DH + d) * SEQL + s0] =
                    *(const uint2*)tmp;
            }
        }
    } else {
        #pragma unroll
        for (int i = 0; i < 4; ++i) {
            #pragma unroll
            for (int rg = 0; rg < 4; ++rg) {
                const int row = bm * 128 + wr * 64 + i * 16 + quad * 4 + rg;
                const int b = row >> 11;
                const int s = row & (SEQL - 1);
                #pragma unroll
                for (int j = 0; j < 4; ++j) {
                    const int col = bn * 128 + wc * 64 + j * 16 + ml;
                    const int h = col >> 6, d = col & 63;
                    outb[(((size_t)(b * NH + h)) * SEQL + s) * DH + d] =
                        __float2bfloat16((acc[i][j][rg] + bb[j]) * oscale);
                }
            }
        }
    }
}

// ---------------------------------------------------------------------------
// O-proj GEMM v3 + XCD-chunked swizzle: the 16 bn-blocks sharing a zb A-panel
// land on one XCD (4 bm panels = 1MB + B 2MB per XCD L2). Body unchanged.
// grid (16,32), block 256.
// ---------------------------------------------------------------------------
__global__ __launch_bounds__(256) void oproj_gemm(
    const bf16* __restrict__ zb, const bf16* __restrict__ Bt,
    const float* __restrict__ bo, float* __restrict__ out)
{
    __shared__ __align__(16) bf16 As[2][128 * 32];
    __shared__ __align__(16) bf16 Bs[2][64 * 32];

    const int t = threadIdx.x;
    const int lane = t & 63, w = t >> 6;
    const int ml = lane & 15, quad = lane >> 4;
    const int wr = w >> 1, wc = w & 1;
    // XCD-chunked swizzle: bid0 in [0,512); XCD x owns L in [64x, 64x+64)
    // -> bm in [4x, 4x+4) contiguous.
    const int bid0 = blockIdx.y * 16 + blockIdx.x;
    const int L = (bid0 & 7) * 64 + (bid0 >> 3);
    const int bn = L & 15, bm = L >> 4;

    const bf16* A0 = zb + (size_t)(bm * 128) * DM;
    const bf16* B0 = Bt + (size_t)(bn * 64) * DM;

    f32x4 acc[4][2];
    #pragma unroll
    for (int i = 0; i < 4; ++i)
        #pragma unroll
        for (int j = 0; j < 2; ++j) acc[i][j] = (f32x4){0.f, 0.f, 0.f, 0.f};

    const int r0 = t >> 2, c0 = (t & 3) * 8;
    const int f1 = t + 256;
    const int r1 = f1 >> 2, c1 = (f1 & 3) * 8;

    for (int kt = 0; kt < DM / 64; ++kt) {
        const int k0 = kt * 64;
        __syncthreads();
        #pragma unroll
        for (int half = 0; half < 2; ++half) {
            const int kh = k0 + half * 32;
            gl_lds16(A0 + (size_t)r0 * DM + kh + c0, &As[half][t * 8]);
            gl_lds16(A0 + (size_t)r1 * DM + kh + c1, &As[half][f1 * 8]);
            gl_lds16(B0 + (size_t)r0 * DM + kh + c0, &Bs[half][t * 8]);
        }
        __syncthreads();
        #pragma unroll
        for (int half = 0; half < 2; ++half) {
            bf16x8 af[4], bfr[2];
            #pragma unroll
            for (int i = 0; i < 4; ++i)
                af[i] = *(const bf16x8*)&As[half][(wr * 64 + i * 16 + ml) * 32 + quad * 8];
            #pragma unroll
            for (int j = 0; j < 2; ++j)
                bfr[j] = *(const bf16x8*)&Bs[half][(wc * 32 + j * 16 + ml) * 32 + quad * 8];
            #pragma unroll
            for (int i = 0; i < 4; ++i)
                #pragma unroll
                for (int j = 0; j < 2; ++j)
                    acc[i][j] = __builtin_amdgcn_mfma_f32_16x16x32_bf16(af[i], bfr[j], acc[i][j], 0, 0, 0);
        }
    }

    float bb[2];
    #pragma unroll
    for (int j = 0; j < 2; ++j) bb[j] = bo[bn * 64 + wc * 32 + j * 16 + ml];

    #pragma unroll
    for (int i = 0; i < 4; ++i) {
        #pragma unroll
        for (int rg = 0; rg < 4; ++rg) {
            const int row = bm * 128 + wr * 64 + i * 16 + quad * 4 + rg;
            #pragma unroll
            for (int j = 0; j < 2; ++j) {
                const int col = bn * 64 + wc * 32 + j * 16 + ml;
                out[(size_t)row * DM + col] = acc[i][j][rg] + bb[j];
            }
        }
    }
}

// ---------------------------------------------------------------------------
// MFMA flash attention v12 = v11 + XCD-chunked block swizzle: the 16 paired
// blocks sharing one (b,h)'s K/V (512KB) now land on the same XCD, so each
// XCD's L2 holds 4 bh's K/V (2MB) instead of thrashing across all 32 bh
// (16MB). Kernel body identical to v11 (128-kv stages, paired q-tiles).
// grid (32, 16) flattened+swizzled, block 512. LDS 51.2 KB.
// ---------------------------------------------------------------------------
__global__ __launch_bounds__(512) void attn_kernel(
    const bf16* __restrict__ qg, const bf16* __restrict__ kg, const bf16* __restrict__ vtg,
    bf16* __restrict__ z)
{
    __shared__ __align__(16) bf16 KsS[128 * 64];     // 16 KB, [kv][d], 8-deep swz
    __shared__ __align__(16) bf16 VtS[64 * 128];     // 16 KB, [d][kv], 16-deep swz
    __shared__ __align__(16) bf16 PsS[8][16 * LDK];  // 18 KB per-wave P tiles

    const int t    = threadIdx.x;
    const int lane = t & 63;
    const int w    = t >> 6;          // 0..7
    const int m    = lane & 15;
    const int quad = lane >> 4;
    const int wg   = w & 3;           // row-group within its tile
    const int half = w >> 2;          // kv half in phase 2

    // XCD-chunked swizzle: bid0 in [0,512); XCD x owns L in [64x, 64x+64)
    // -> bh in [4x, 4x+4): each XCD's L2 caches 4 bh's K/V (2MB).
    const int bid0 = blockIdx.y * 32 + blockIdx.x;
    const int L = (bid0 & 7) * 64 + (bid0 >> 3);
    const int bh = L >> 4;            // 0..31
    const int qa = L & 15;            // 0..15
    const int b  = bh >> 4;
    const int h  = bh & 15;
    const int qb = 31 - qa;           // 16..31
    const int q0a = qa * 64;
    const int q0b = qb * 64;

    const size_t base   = (size_t)bh * SEQL * DH;  // q/k base ([b,h,s,d])
    const size_t vtbase = (size_t)bh * DH * SEQL;  // v^T base ([b,h,d,s])

    // staging slots: 512 thr x 2 slots x 16B per array (1024 slots = 16KB each)
    const int s0 = t, s1 = t + 512;
    const int kr0 = s0 >> 3, kc0 = (s0 & 7) ^ (kr0 & 7);
    const int kr1 = s1 >> 3, kc1 = (s1 & 7) ^ (kr1 & 7);
    const int vr0 = s0 >> 4, vc0 = (s0 & 15) ^ (vr0 & 15);
    const int vr1 = s1 >> 4, vc1 = (s1 & 15) ^ (vr1 & 15);

    bf16x8 aq[2], aqB[2];
    {
        const int myq = (w < 4) ? (q0a + w * 16) : (q0b + wg * 16);
        const bf16* qp = qg + base + (size_t)(myq + m) * DH + quad * 8;
        aq[0] = *(const bf16x8*)(qp);
        aq[1] = *(const bf16x8*)(qp + 32);
        const bf16* qpb = qg + base + (size_t)(q0b + wg * 16 + m) * DH + quad * 8;
        aqB[0] = *(const bf16x8*)(qpb);
        aqB[1] = *(const bf16x8*)(qpb + 32);
    }

    const short ob = (m == 0) ? (short)0x3F80 : (short)0;
    const bf16x8 bones = {ob, ob, ob, ob, ob, ob, ob, ob};

    f32x4 zacc[4];
    #pragma unroll
    for (int nt = 0; nt < 4; ++nt) zacc[nt] = (f32x4){0.f, 0.f, 0.f, 0.f};
    f32x4 lacc = (f32x4){0.f, 0.f, 0.f, 0.f};

    bf16* Psw = PsS[w];

    const int CB = (qb >> 1) + 1;     // 128-kv stages
    for (int c = 0; c < CB; ++c) {
        __syncthreads();              // prev stage's reads complete
        {
            const int kc = c * 128;
            gl_lds16(kg + base + (size_t)(kc + kr0) * DH + kc0 * 8, &KsS[s0 * 8]);
            gl_lds16(kg + base + (size_t)(kc + kr1) * DH + kc1 * 8, &KsS[s1 * 8]);
            gl_lds16(vtg + vtbase + (size_t)vr0 * SEQL + kc + vc0 * 8, &VtS[s0 * 8]);
            gl_lds16(vtg + vtbase + (size_t)vr1 * SEQL + kc + vc1 * 8, &VtS[s1 * 8]);
        }
        __syncthreads();              // staging visible (vmcnt drain)

        #pragma unroll
        for (int c2 = 0; c2 < 2; ++c2) {
            const int kt = 2 * c + c2;
            if (kt > qb) break;       // uniform across block
            const int co = c2 * 64;   // kv row offset within the stage

            if (kt <= qa) {
                // ---------- phase 1: waves 0-3 tile a, 4-7 tile b ----------
                f32x4 sc[4];
                #pragma unroll
                for (int nt = 0; nt < 4; ++nt) sc[nt] = (f32x4){0.f, 0.f, 0.f, 0.f};
                __builtin_amdgcn_s_setprio(1);
                #pragma unroll
                for (int ks = 0; ks < 2; ++ks) {
                    #pragma unroll
                    for (int nt = 0; nt < 4; ++nt) {
                        const int rw = co + nt * 16 + m;
                        const int pc = ((ks << 2) + quad) ^ (m & 7);
                        const bf16x8 bk = *(const bf16x8*)(&KsS[rw * 64 + pc * 8]);
                        sc[nt] = __builtin_amdgcn_mfma_f32_16x16x32_bf16(aq[ks], bk, sc[nt], 0, 0, 0);
                    }
                }
                __builtin_amdgcn_s_setprio(0);
                if (kt == qa && w < 4) {
                    #pragma unroll
                    for (int nt = 0; nt < 4; ++nt) {
                        const int col = nt * 16 + m;
                        #pragma unroll
                        for (int rg = 0; rg < 4; ++rg) {
                            const int row = wg * 16 + quad * 4 + rg;
                            if (col > row) sc[nt][rg] = -1e30f;
                        }
                    }
                }

                #pragma unroll
                for (int nt = 0; nt < 4; ++nt)
                    #pragma unroll
                    for (int rg = 0; rg < 4; ++rg)
                        Psw[(quad * 4 + rg) * LDK + nt * 16 + m] =
                            __float2bfloat16(__builtin_exp2f(sc[nt][rg]));

                __builtin_amdgcn_s_setprio(1);
                #pragma unroll
                for (int ks = 0; ks < 2; ++ks) {
                    const bf16x8 ap = *(const bf16x8*)(&Psw[m * LDK + ks * 32 + quad * 8]);
                    lacc = __builtin_amdgcn_mfma_f32_16x16x32_bf16(ap, bones, lacc, 0, 0, 0);
                    #pragma unroll
                    for (int nt = 0; nt < 4; ++nt) {
                        const int dr = nt * 16 + m;
                        const int vc = (c2 * 8 + (ks << 2) + quad) ^ m;
                        const bf16x8 bv = *(const bf16x8*)(&VtS[dr * 128 + vc * 8]);
                        zacc[nt] = __builtin_amdgcn_mfma_f32_16x16x32_bf16(ap, bv, zacc[nt], 0, 0, 0);
                    }
                }
                __builtin_amdgcn_s_setprio(0);

                if (kt == qa && w < 4) {
                    // finalize + write tile a, switch to tile b
                    float invl[4];
                    #pragma unroll
                    for (int rg = 0; rg < 4; ++rg)
                        invl[rg] = 1.f / __shfl(lacc[rg], quad * 16);
                    #pragma unroll
                    for (int nt = 0; nt < 4; ++nt) {
                        const int d = nt * 16 + m;
                        #pragma unroll
                        for (int rg = 0; rg < 4; ++rg) {
                            const int qrow = q0a + wg * 16 + quad * 4 + rg;
                            z[(((size_t)b * SEQL + qrow) * NH + h) * DH + d] =
                                __float2bfloat16(zacc[nt][rg] * invl[rg]);
                        }
                    }
                    #pragma unroll
                    for (int nt = 0; nt < 4; ++nt) zacc[nt] = (f32x4){0.f, 0.f, 0.f, 0.f};
                    lacc = (f32x4){0.f, 0.f, 0.f, 0.f};
                    aq[0] = aqB[0]; aq[1] = aqB[1];
                }
            } else {
                // ---------- phase 2: all 8 waves on tile b, kv halves split ----
                f32x4 sc[2];
                sc[0] = (f32x4){0.f, 0.f, 0.f, 0.f};
                sc[1] = (f32x4){0.f, 0.f, 0.f, 0.f};
                __builtin_amdgcn_s_setprio(1);
                #pragma unroll
                for (int ks = 0; ks < 2; ++ks) {
                    #pragma unroll
                    for (int nt = 0; nt < 2; ++nt) {
                        const int rw = co + half * 32 + nt * 16 + m;
                        const int pc = ((ks << 2) + quad) ^ (m & 7);
                        const bf16x8 bk = *(const bf16x8*)(&KsS[rw * 64 + pc * 8]);
                        sc[nt] = __builtin_amdgcn_mfma_f32_16x16x32_bf16(aq[ks], bk, sc[nt], 0, 0, 0);
                    }
                }
                __builtin_amdgcn_s_setprio(0);
                if (kt == qb) {
                    #pragma unroll
                    for (int nt = 0; nt < 2; ++nt) {
                        const int col = half * 32 + nt * 16 + m;
                        #pragma unroll
                        for (int rg = 0; rg < 4; ++rg) {
                            const int row = wg * 16 + quad * 4 + rg;
                            if (col > row) sc[nt][rg] = -1e30f;
                        }
                    }
                }

                #pragma unroll
                for (int nt = 0; nt < 2; ++nt)
                    #pragma unroll
                    for (int rg = 0; rg < 4; ++rg)
                        Psw[(quad * 4 + rg) * LDK + nt * 16 + m] =
                            __float2bfloat16(__builtin_exp2f(sc[nt][rg]));

                __builtin_amdgcn_s_setprio(1);
                {
                    const bf16x8 ap = *(const bf16x8*)(&Psw[m * LDK + quad * 8]);
                    lacc = __builtin_amdgcn_mfma_f32_16x16x32_bf16(ap, bones, lacc, 0, 0, 0);
                    #pragma unroll
                    for (int nt = 0; nt < 4; ++nt) {
                        const int dr = nt * 16 + m;
                        const int vc = (c2 * 8 + (half << 2) + quad) ^ m;
                        const bf16x8 bv = *(const bf16x8*)(&VtS[dr * 128 + vc * 8]);
                        zacc[nt] = __builtin_amdgcn_mfma_f32_16x16x32_bf16(ap, bv, zacc[nt], 0, 0, 0);
                    }
                }
                __builtin_amdgcn_s_setprio(0);
            }
        }
    }

    // ---- combine tile b partials across wave pairs (w, w+4) via LDS ----
    __syncthreads();   // all compute done; K/V LDS reusable as f32 scratch
    if (w < 4) {
        float* zs = (w < 2) ? ((float*)KsS) + (size_t)w * 1024
                            : ((float*)VtS) + (size_t)(w - 2) * 1024;
        #pragma unroll
        for (int nt = 0; nt < 4; ++nt)
            #pragma unroll
            for (int rg = 0; rg < 4; ++rg)
                zs[lane * 16 + nt * 4 + rg] = zacc[nt][rg];
        float* ls = ((float*)PsS) + w * 256;
        #pragma unroll
        for (int rg = 0; rg < 4; ++rg) ls[lane * 4 + rg] = lacc[rg];
    }
    __syncthreads();
    if (w >= 4) {
        const int ww = w - 4;
        const float* zs = (ww < 2) ? ((const float*)KsS) + (size_t)ww * 1024
                                   : ((const float*)VtS) + (size_t)(ww - 2) * 1024;
        const float* ls = ((const float*)PsS) + ww * 256;
        #pragma unroll
        for (int nt = 0; nt < 4; ++nt)
            #pragma unroll
            for (int rg = 0; rg < 4; ++rg)
                zacc[nt][rg] += zs[lane * 16 + nt * 4 + rg];
        #pragma unroll
        for (int rg = 0; rg < 4; ++rg) lacc[rg] += ls[lane * 4 + rg];

        float invl[4];
        #pragma unroll
        for (int rg = 0; rg < 4; ++rg)
            invl[rg] = 1.f / __shfl(lacc[rg], quad * 16);
        #pragma unroll
        for (int nt = 0; nt < 4; ++nt) {
            const int d = nt * 16 + m;
            #pragma unroll
            for (int rg = 0; rg < 4; ++rg) {
                const int qrow = q0b + wg * 16 + quad * 4 + rg;
                z[(((size_t)b * SEQL + qrow) * NH + h) * DH + d] =
                    __float2bfloat16(zacc[nt][rg] * invl[rg]);
            }
        }
    }
}

// ---------------------------------------------------------------------------
extern "C" void kernel_launch(void* const* d_in, const int* in_sizes, int n_in,
                              void* d_out, int out_size, void* d_ws, size_t ws_size,
                              hipStream_t stream)
{
    const float* x  = (const float*)d_in[0];
    const float* Wq = (const float*)d_in[1];
    const float* Wk = (const float*)d_in[2];
    const float* Wv = (const float*)d_in[3];
    const float* Wo = (const float*)d_in[4];
    const float* bq = (const float*)d_in[5];
    const float* bk = (const float*)d_in[6];
    const float* bv = (const float*)d_in[7];
    const float* bo = (const float*)d_in[8];
    float* out = (float*)d_out;

    const size_t TOK = (size_t)BATCH * SEQL;             // 4096
    const size_t QKV = TOK * DM;                         // 4M elems
    bf16* xb  = (bf16*)d_ws;                             // 4M
    bf16* Wt  = xb + QKV;                                // 4 x 1M
    bf16* qkv = Wt + 4 * (size_t)DM * DM;                // 3 x 4M
    bf16* zb  = qkv + 3 * QKV;                           // 4M   (48 MB total)

    prep_kernel<<<dim3(16, 16, 5), 256, 0, stream>>>(x, Wq, Wk, Wv, Wo, Wt, xb);
    qkv_gemm<<<dim3(8, 32, 3), 256, 0, stream>>>(xb, Wt, bq, bk, bv, qkv);
    attn_kernel<<<dim3(32, 16), 512, 0, stream>>>(
        qkv, qkv + QKV, qkv + 2 * QKV, zb);
    oproj_gemm<<<dim3(16, 32), 256, 0, stream>>>(zb, Wt + 3 * (size_t)DM * DM, bo, out);
}

// Round 9
// 181.843 us; speedup vs baseline: 1.0114x; 1.0114x over previous
//
#include <hip/hip_runtime.h>
#include <hip/hip_bf16.h>

#define BATCH 2
#define SEQL 2048
#define NH 16
#define DH 64
#define DM 1024
#define LDK 72   // attn P-tile LDS row stride (bf16): 144B rows -> 2-way (free)
// Q pre-scale folded into qkv_gemm epilogue: 1/sqrt(64) * log2(e)
#define QSCALE 0.1803368801111244f

typedef __hip_bfloat16 bf16;
typedef __attribute__((ext_vector_type(8)))  short bf16x8;
typedef __attribute__((ext_vector_type(4)))  float f32x4;

__device__ __forceinline__ void gl_lds16(const void* g, void* l) {
    __builtin_amdgcn_global_load_lds(
        (const __attribute__((address_space(1))) unsigned int*)g,
        (__attribute__((address_space(3))) unsigned int*)l, 16, 0, 0);
}

// ---------------------------------------------------------------------------
// Prep (fused): z<4 -> weight transpose to bf16 Bt[n][k]; z==4 -> x fp32->bf16
// (grid-stride). grid (16,16,5), block 256.
// ---------------------------------------------------------------------------
__global__ __launch_bounds__(256) void prep_kernel(
    const float* __restrict__ x,
    const float* __restrict__ Wq, const float* __restrict__ Wk,
    const float* __restrict__ Wv, const float* __restrict__ Wo,
    bf16* __restrict__ Wt, bf16* __restrict__ xb)
{
    const int zi = blockIdx.z;
    if (zi == 4) {
        const int bid = blockIdx.y * 16 + blockIdx.x;
        const size_t base = ((size_t)bid * 256 + threadIdx.x) * 4;
        #pragma unroll
        for (int it = 0; it < 16; ++it) {
            const size_t i = base + (size_t)it * 262144;
            const float4 v = *(const float4*)(x + i);
            bf16 o[4];
            o[0] = __float2bfloat16(v.x); o[1] = __float2bfloat16(v.y);
            o[2] = __float2bfloat16(v.z); o[3] = __float2bfloat16(v.w);
            *(uint2*)(xb + i) = *(const uint2*)o;
        }
        return;
    }

    __shared__ float ts[64][65];
    const float* src = (zi == 0) ? Wq : (zi == 1) ? Wk : (zi == 2) ? Wv : Wo;
    bf16* dst = Wt + (size_t)zi * DM * DM;
    const int row0 = blockIdx.y * 64;
    const int col0 = blockIdx.x * 64;
    const int tx = threadIdx.x & 63;
    const int ty = threadIdx.x >> 6;

    if (zi < 3) {
        const int h = col0 >> 6;
        #pragma unroll
        for (int i = 0; i < 16; ++i) {
            const int r = ty + 4 * i;
            ts[r][tx] = src[h * (DM * DH) + (row0 + r) * DH + tx];
        }
    } else {
        #pragma unroll
        for (int i = 0; i < 16; ++i) {
            const int r = ty + 4 * i;
            ts[r][tx] = src[(size_t)(row0 + r) * DM + col0 + tx];
        }
    }
    __syncthreads();
    #pragma unroll
    for (int i = 0; i < 16; ++i) {
        const int rr = ty + 4 * i;
        dst[(size_t)(col0 + rr) * DM + row0 + tx] = __float2bfloat16(ts[tx][rr]);
    }
}

// ---------------------------------------------------------------------------
// QKV GEMM v3 + XCD-chunked block swizzle (kept: r8 showed non-attn -1.4us).
// grid (8, 32, 3), block 256.
// ---------------------------------------------------------------------------
__global__ __launch_bounds__(256) void qkv_gemm(
    const bf16* __restrict__ xb, const bf16* __restrict__ Wt,
    const float* __restrict__ bq, const float* __restrict__ bk, const float* __restrict__ bv,
    bf16* __restrict__ qkv)
{
    __shared__ __align__(16) bf16 As[2][128 * 32];
    __shared__ __align__(16) bf16 Bs[2][128 * 32];

    const int t = threadIdx.x;
    const int lane = t & 63, w = t >> 6;
    const int ml = lane & 15, quad = lane >> 4;
    const int wr = w >> 1, wc = w & 1;
    const int bid0 = blockIdx.y * 8 + blockIdx.x;
    const int L = (bid0 & 7) * 32 + (bid0 >> 3);
    const int bn = L & 7, bm = L >> 3;
    const int which = blockIdx.z;

    const bf16* A0 = xb + (size_t)(bm * 128) * DM;
    const bf16* B0 = Wt + (size_t)which * DM * DM + (size_t)(bn * 128) * DM;
    const float* bias = (which == 0) ? bq : (which == 1) ? bk : bv;
    bf16* outb = qkv + (size_t)which * (BATCH * SEQL * NH * DH);
    const float oscale = (which == 0) ? QSCALE : 1.0f;

    f32x4 acc[4][4];
    #pragma unroll
    for (int i = 0; i < 4; ++i)
        #pragma unroll
        for (int j = 0; j < 4; ++j) acc[i][j] = (f32x4){0.f, 0.f, 0.f, 0.f};

    const int r0 = t >> 2, c0 = (t & 3) * 8;
    const int f1 = t + 256;
    const int r1 = f1 >> 2, c1 = (f1 & 3) * 8;

    for (int kt = 0; kt < DM / 64; ++kt) {
        const int k0 = kt * 64;
        __syncthreads();
        #pragma unroll
        for (int half = 0; half < 2; ++half) {
            const int kh = k0 + half * 32;
            gl_lds16(A0 + (size_t)r0 * DM + kh + c0, &As[half][t * 8]);
            gl_lds16(A0 + (size_t)r1 * DM + kh + c1, &As[half][f1 * 8]);
            gl_lds16(B0 + (size_t)r0 * DM + kh + c0, &Bs[half][t * 8]);
            gl_lds16(B0 + (size_t)r1 * DM + kh + c1, &Bs[half][f1 * 8]);
        }
        __syncthreads();
        #pragma unroll
        for (int half = 0; half < 2; ++half) {
            bf16x8 af[4], bfr[4];
            #pragma unroll
            for (int i = 0; i < 4; ++i)
                af[i] = *(const bf16x8*)&As[half][(wr * 64 + i * 16 + ml) * 32 + quad * 8];
            #pragma unroll
            for (int j = 0; j < 4; ++j)
                bfr[j] = *(const bf16x8*)&Bs[half][(wc * 64 + j * 16 + ml) * 32 + quad * 8];
            #pragma unroll
            for (int i = 0; i < 4; ++i)
                #pragma unroll
                for (int j = 0; j < 4; ++j)
                    acc[i][j] = __builtin_amdgcn_mfma_f32_16x16x32_bf16(af[i], bfr[j], acc[i][j], 0, 0, 0);
        }
    }

    float bb[4];
    #pragma unroll
    for (int j = 0; j < 4; ++j) bb[j] = bias[bn * 128 + wc * 64 + j * 16 + ml];

    if (which == 2) {
        #pragma unroll
        for (int i = 0; i < 4; ++i) {
            const int row0v = bm * 128 + wr * 64 + i * 16 + quad * 4;
            const int b = row0v >> 11;
            const int s0 = row0v & (SEQL - 1);
            #pragma unroll
            for (int j = 0; j < 4; ++j) {
                const int col = bn * 128 + wc * 64 + j * 16 + ml;
                const int h = col >> 6, d = col & 63;
                bf16 tmp[4];
                #pragma unroll
                for (int rg = 0; rg < 4; ++rg)
                    tmp[rg] = __float2bfloat16(acc[i][j][rg] + bb[j]);
                *(uint2*)&outb[(((size_t)(b * NH + h)) * DH + d) * SEQL + s0] =
                    *(const uint2*)tmp;
            }
        }
    } else {
        #pragma unroll
        for (int i = 0; i < 4; ++i) {
            #pragma unroll
            for (int rg = 0; rg < 4; ++rg) {
                const int row = bm * 128 + wr * 64 + i * 16 + quad * 4 + rg;
                const int b = row >> 11;
                const int s = row & (SEQL - 1);
                #pragma unroll
                for (int j = 0; j < 4; ++j) {
                    const int col = bn * 128 + wc * 64 + j * 16 + ml;
                    const int h = col >> 6, d = col & 63;
                    outb[(((size_t)(b * NH + h)) * SEQL + s) * DH + d] =
                        __float2bfloat16((acc[i][j][rg] + bb[j]) * oscale);
                }
            }
        }
    }
}

// ---------------------------------------------------------------------------
// O-proj GEMM v3 + XCD-chunked swizzle (kept). grid (16,32), block 256.
// ---------------------------------------------------------------------------
__global__ __launch_bounds__(256) void oproj_gemm(
    const bf16* __restrict__ zb, const bf16* __restrict__ Bt,
    const float* __restrict__ bo, float* __restrict__ out)
{
    __shared__ __align__(16) bf16 As[2][128 * 32];
    __shared__ __align__(16) bf16 Bs[2][64 * 32];

    const int t = threadIdx.x;
    const int lane = t & 63, w = t >> 6;
    const int ml = lane & 15, quad = lane >> 4;
    const int wr = w >> 1, wc = w & 1;
    const int bid0 = blockIdx.y * 16 + blockIdx.x;
    const int L = (bid0 & 7) * 64 + (bid0 >> 3);
    const int bn = L & 15, bm = L >> 4;

    const bf16* A0 = zb + (size_t)(bm * 128) * DM;
    const bf16* B0 = Bt + (size_t)(bn * 64) * DM;

    f32x4 acc[4][2];
    #pragma unroll
    for (int i = 0; i < 4; ++i)
        #pragma unroll
        for (int j = 0; j < 2; ++j) acc[i][j] = (f32x4){0.f, 0.f, 0.f, 0.f};

    const int r0 = t >> 2, c0 = (t & 3) * 8;
    const int f1 = t + 256;
    const int r1 = f1 >> 2, c1 = (f1 & 3) * 8;

    for (int kt = 0; kt < DM / 64; ++kt) {
        const int k0 = kt * 64;
        __syncthreads();
        #pragma unroll
        for (int half = 0; half < 2; ++half) {
            const int kh = k0 + half * 32;
            gl_lds16(A0 + (size_t)r0 * DM + kh + c0, &As[half][t * 8]);
            gl_lds16(A0 + (size_t)r1 * DM + kh + c1, &As[half][f1 * 8]);
            gl_lds16(B0 + (size_t)r0 * DM + kh + c0, &Bs[half][t * 8]);
        }
        __syncthreads();
        #pragma unroll
        for (int half = 0; half < 2; ++half) {
            bf16x8 af[4], bfr[2];
            #pragma unroll
            for (int i = 0; i < 4; ++i)
                af[i] = *(const bf16x8*)&As[half][(wr * 64 + i * 16 + ml) * 32 + quad * 8];
            #pragma unroll
            for (int j = 0; j < 2; ++j)
                bfr[j] = *(const bf16x8*)&Bs[half][(wc * 32 + j * 16 + ml) * 32 + quad * 8];
            #pragma unroll
            for (int i = 0; i < 4; ++i)
                #pragma unroll
                for (int j = 0; j < 2; ++j)
                    acc[i][j] = __builtin_amdgcn_mfma_f32_16x16x32_bf16(af[i], bfr[j], acc[i][j], 0, 0, 0);
        }
    }

    float bb[2];
    #pragma unroll
    for (int j = 0; j < 2; ++j) bb[j] = bo[bn * 64 + wc * 32 + j * 16 + ml];

    #pragma unroll
    for (int i = 0; i < 4; ++i) {
        #pragma unroll
        for (int rg = 0; rg < 4; ++rg) {
            const int row = bm * 128 + wr * 64 + i * 16 + quad * 4 + rg;
            #pragma unroll
            for (int j = 0; j < 2; ++j) {
                const int col = bn * 64 + wc * 32 + j * 16 + ml;
                out[(size_t)row * DM + col] = acc[i][j][rg] + bb[j];
            }
        }
    }
}

// ---------------------------------------------------------------------------
// MFMA flash attention v13: DS-PIPE AMORTIZATION. Model: v11 was LDS-pipe
// bound (~2470 DS cy/block-iter vs 2383 measured wall). Fix: each wave owns
// TWO 16-row q-groups (32 q rows, Q in regs); every K/V ds_read_b128 feeds 2
// MFMAs -> per-q-row DS drops 1.45x. Tiles are 128 q-rows, paired (a, 15-a):
// wall = (2a+2) + (30-4a)/2 = 17 full-cost 64-kv iters for EVERY block.
// Grid 256 blocks = 1/CU (DS is per-CU shared: occupancy irrelevant under
// the model); K/V double-buffered at 128-kv granularity with prefetch
// issued before compute (free at 1 block/CU; hides the vmcnt drain).
// Phase1: waves 0-3 tile a, 4-7 tile b (full 64 kv). At kt==2a+1 waves 0-3
// finalize tile a and adopt tile b rows; phase2 splits kv halves across
// (w, w+4); partials combined via LDS at the end.
// grid (bh=32, pair=8), block 512. LDS 101 KB, VGPR-bound (512,2).
// ---------------------------------------------------------------------------
__global__ __launch_bounds__(512, 2) void attn_kernel(
    const bf16* __restrict__ qg, const bf16* __restrict__ kg, const bf16* __restrict__ vtg,
    bf16* __restrict__ z)
{
    __shared__ __align__(16) bf16 KsS[2][128 * 64];   // 2 x 16 KB, [kv][d] swz8
    __shared__ __align__(16) bf16 VtS[2][64 * 128];   // 2 x 16 KB, [d][kv] swz16
    __shared__ __align__(16) bf16 PsS[8][32 * LDK];   // 36 KB per-wave P tiles

    const int t    = threadIdx.x;
    const int lane = t & 63;
    const int w    = t >> 6;          // 0..7
    const int m    = lane & 15;
    const int quad = lane >> 4;
    const int wg   = w & 3;           // row-group-of-4 within its tile
    const int half = w >> 2;          // kv half in phase 2

    const int bh = blockIdx.x;
    const int b0 = bh >> 4;
    const int h  = bh & 15;
    const int pa = blockIdx.y;        // 0..7  (tile a index, 128-row tiles)
    const int pb = 15 - pa;           // 8..15 (tile b)
    const int lastA = 2 * pa + 1;     // last 64-kv iter for tile a
    // kt runs 0 .. 2*pb+1

    const size_t base   = (size_t)bh * SEQL * DH;  // q/k base ([b,h,s,d])
    const size_t vtbase = (size_t)bh * DH * SEQL;  // v^T base ([b,h,d,s])

    // staging slots: 512 thr x 2 slots x 16B per array (1024 slots = 16KB each)
    const int s0 = t, s1 = t + 512;
    const int kr0 = s0 >> 3, kc0 = (s0 & 7) ^ (kr0 & 7);
    const int kr1 = s1 >> 3, kc1 = (s1 & 7) ^ (kr1 & 7);
    const int vr0 = s0 >> 4, vc0 = (s0 & 15) ^ (vr0 & 15);
    const int vr1 = s1 >> 4, vc1 = (s1 & 15) ^ (vr1 & 15);

    const int myTile0 = (w < 4) ? pa : pb;
    int tile = myTile0;               // current tile of this wave (a -> b)

    bf16x8 aq[2][2], aqB[2][2];
    #pragma unroll
    for (int g = 0; g < 2; ++g) {
        const bf16* qp = qg + base +
            (size_t)(myTile0 * 128 + g * 64 + wg * 16 + m) * DH + quad * 8;
        aq[g][0] = *(const bf16x8*)(qp);
        aq[g][1] = *(const bf16x8*)(qp + 32);
        const bf16* qpb = qg + base +
            (size_t)(pb * 128 + g * 64 + wg * 16 + m) * DH + quad * 8;
        aqB[g][0] = *(const bf16x8*)(qpb);
        aqB[g][1] = *(const bf16x8*)(qpb + 32);
    }

    const short ob = (m == 0) ? (short)0x3F80 : (short)0;
    const bf16x8 bones = {ob, ob, ob, ob, ob, ob, ob, ob};

    f32x4 zacc[2][4];
    f32x4 lacc[2];
    #pragma unroll
    for (int g = 0; g < 2; ++g) {
        #pragma unroll
        for (int nt = 0; nt < 4; ++nt) zacc[g][nt] = (f32x4){0.f, 0.f, 0.f, 0.f};
        lacc[g] = (f32x4){0.f, 0.f, 0.f, 0.f};
    }

    bf16* Psw = PsS[w];

    const int CB = 16 - pa;           // 128-kv stages; kt max = 2*CB-1 = 2*pb+1

    // ---- prologue: stage 0 into buffer 0 ----
    gl_lds16(kg + base + (size_t)kr0 * DH + kc0 * 8, &KsS[0][s0 * 8]);
    gl_lds16(kg + base + (size_t)kr1 * DH + kc1 * 8, &KsS[0][s1 * 8]);
    gl_lds16(vtg + vtbase + (size_t)vr0 * SEQL + vc0 * 8, &VtS[0][s0 * 8]);
    gl_lds16(vtg + vtbase + (size_t)vr1 * SEQL + vc1 * 8, &VtS[0][s1 * 8]);

    for (int c = 0; c < CB; ++c) {
        __syncthreads();              // drains gl_lds (stage c) + frees buf c^1
        if (c + 1 < CB) {             // prefetch stage c+1 (hidden under compute)
            const int kc = (c + 1) * 128;
            bf16* Kd = &KsS[(c + 1) & 1][0];
            bf16* Vd = &VtS[(c + 1) & 1][0];
            gl_lds16(kg + base + (size_t)(kc + kr0) * DH + kc0 * 8, Kd + s0 * 8);
            gl_lds16(kg + base + (size_t)(kc + kr1) * DH + kc1 * 8, Kd + s1 * 8);
            gl_lds16(vtg + vtbase + (size_t)vr0 * SEQL + kc + vc0 * 8, Vd + s0 * 8);
            gl_lds16(vtg + vtbase + (size_t)vr1 * SEQL + kc + vc1 * 8, Vd + s1 * 8);
        }
        const bf16* Ks = &KsS[c & 1][0];
        const bf16* Vt = &VtS[c & 1][0];

        #pragma unroll
        for (int c2 = 0; c2 < 2; ++c2) {
            const int kt = 2 * c + c2;
            const int co = c2 * 64;

            if (kt <= lastA) {
                // ---------- phase 1: full 64 kv; 2 q-groups per wave ----------
                f32x4 sc[2][4];
                #pragma unroll
                for (int g = 0; g < 2; ++g)
                    #pragma unroll
                    for (int nt = 0; nt < 4; ++nt) sc[g][nt] = (f32x4){0.f, 0.f, 0.f, 0.f};
                __builtin_amdgcn_s_setprio(1);
                #pragma unroll
                for (int ks = 0; ks < 2; ++ks) {
                    #pragma unroll
                    for (int nt = 0; nt < 4; ++nt) {
                        const int rw = co + nt * 16 + m;
                        const int pc = ((ks << 2) + quad) ^ (m & 7);
                        const bf16x8 bk = *(const bf16x8*)(&Ks[rw * 64 + pc * 8]);
                        sc[0][nt] = __builtin_amdgcn_mfma_f32_16x16x32_bf16(aq[0][ks], bk, sc[0][nt], 0, 0, 0);
                        sc[1][nt] = __builtin_amdgcn_mfma_f32_16x16x32_bf16(aq[1][ks], bk, sc[1][nt], 0, 0, 0);
                    }
                }
                __builtin_amdgcn_s_setprio(0);

                // causal mask per group (wave-uniform gate)
                #pragma unroll
                for (int g = 0; g < 2; ++g) {
                    if (kt >= 2 * tile + g) {
                        #pragma unroll
                        for (int nt = 0; nt < 4; ++nt) {
                            const int kv = kt * 64 + nt * 16 + m;
                            #pragma unroll
                            for (int rg = 0; rg < 4; ++rg) {
                                const int qr = tile * 128 + g * 64 + wg * 16 + quad * 4 + rg;
                                if (kv > qr) sc[g][nt][rg] = -1e30f;
                            }
                        }
                    }
                }

                // p = 2^s
                #pragma unroll
                for (int g = 0; g < 2; ++g)
                    #pragma unroll
                    for (int nt = 0; nt < 4; ++nt)
                        #pragma unroll
                        for (int rg = 0; rg < 4; ++rg)
                            Psw[(g * 16 + quad * 4 + rg) * LDK + nt * 16 + m] =
                                __float2bfloat16(__builtin_exp2f(sc[g][nt][rg]));

                // Z += P V, l += P * ones (V/K frags shared across 2 groups)
                __builtin_amdgcn_s_setprio(1);
                #pragma unroll
                for (int ks = 0; ks < 2; ++ks) {
                    const bf16x8 ap0 = *(const bf16x8*)(&Psw[(m) * LDK + ks * 32 + quad * 8]);
                    const bf16x8 ap1 = *(const bf16x8*)(&Psw[(16 + m) * LDK + ks * 32 + quad * 8]);
                    lacc[0] = __builtin_amdgcn_mfma_f32_16x16x32_bf16(ap0, bones, lacc[0], 0, 0, 0);
                    lacc[1] = __builtin_amdgcn_mfma_f32_16x16x32_bf16(ap1, bones, lacc[1], 0, 0, 0);
                    #pragma unroll
                    for (int nt = 0; nt < 4; ++nt) {
                        const int dr = nt * 16 + m;
                        const int vc = (c2 * 8 + (ks << 2) + quad) ^ m;
                        const bf16x8 bv = *(const bf16x8*)(&Vt[dr * 128 + vc * 8]);
                        zacc[0][nt] = __builtin_amdgcn_mfma_f32_16x16x32_bf16(ap0, bv, zacc[0][nt], 0, 0, 0);
                        zacc[1][nt] = __builtin_amdgcn_mfma_f32_16x16x32_bf16(ap1, bv, zacc[1][nt], 0, 0, 0);
                    }
                }
                __builtin_amdgcn_s_setprio(0);

                if (kt == lastA && w < 4) {
                    // ---- finalize + write tile a (both groups), adopt tile b ----
                    #pragma unroll
                    for (int g = 0; g < 2; ++g) {
                        float invl[4];
                        #pragma unroll
                        for (int rg = 0; rg < 4; ++rg)
                            invl[rg] = 1.f / __shfl(lacc[g][rg], quad * 16);
                        #pragma unroll
                        for (int nt = 0; nt < 4; ++nt) {
                            const int d = nt * 16 + m;
                            #pragma unroll
                            for (int rg = 0; rg < 4; ++rg) {
                                const int qrow = pa * 128 + g * 64 + wg * 16 + quad * 4 + rg;
                                z[(((size_t)b0 * SEQL + qrow) * NH + h) * DH + d] =
                                    __float2bfloat16(zacc[g][nt][rg] * invl[rg]);
                            }
                        }
                        #pragma unroll
                        for (int nt = 0; nt < 4; ++nt) zacc[g][nt] = (f32x4){0.f, 0.f, 0.f, 0.f};
                        lacc[g] = (f32x4){0.f, 0.f, 0.f, 0.f};
                        aq[g][0] = aqB[g][0]; aq[g][1] = aqB[g][1];
                    }
                    tile = pb;
                }
            } else {
                // ---------- phase 2: all 8 waves tile b, kv halves split ----------
                f32x4 sc[2][2];
                #pragma unroll
                for (int g = 0; g < 2; ++g)
                    #pragma unroll
                    for (int nt = 0; nt < 2; ++nt) sc[g][nt] = (f32x4){0.f, 0.f, 0.f, 0.f};
                __builtin_amdgcn_s_setprio(1);
                #pragma unroll
                for (int ks = 0; ks < 2; ++ks) {
                    #pragma unroll
                    for (int nt = 0; nt < 2; ++nt) {
                        const int rw = co + half * 32 + nt * 16 + m;
                        const int pc = ((ks << 2) + quad) ^ (m & 7);
                        const bf16x8 bk = *(const bf16x8*)(&Ks[rw * 64 + pc * 8]);
                        sc[0][nt] = __builtin_amdgcn_mfma_f32_16x16x32_bf16(aq[0][ks], bk, sc[0][nt], 0, 0, 0);
                        sc[1][nt] = __builtin_amdgcn_mfma_f32_16x16x32_bf16(aq[1][ks], bk, sc[1][nt], 0, 0, 0);
                    }
                }
                __builtin_amdgcn_s_setprio(0);

                #pragma unroll
                for (int g = 0; g < 2; ++g) {
                    if (kt >= 2 * pb + g) {
                        #pragma unroll
                        for (int nt = 0; nt < 2; ++nt) {
                            const int kv = kt * 64 + half * 32 + nt * 16 + m;
                            #pragma unroll
                            for (int rg = 0; rg < 4; ++rg) {
                                const int qr = pb * 128 + g * 64 + wg * 16 + quad * 4 + rg;
                                if (kv > qr) sc[g][nt][rg] = -1e30f;
                            }
                        }
                    }
                }

                #pragma unroll
                for (int g = 0; g < 2; ++g)
                    #pragma unroll
                    for (int nt = 0; nt < 2; ++nt)
                        #pragma unroll
                        for (int rg = 0; rg < 4; ++rg)
                            Psw[(g * 16 + quad * 4 + rg) * LDK + nt * 16 + m] =
                                __float2bfloat16(__builtin_exp2f(sc[g][nt][rg]));

                __builtin_amdgcn_s_setprio(1);
                {
                    const bf16x8 ap0 = *(const bf16x8*)(&Psw[(m) * LDK + quad * 8]);
                    const bf16x8 ap1 = *(const bf16x8*)(&Psw[(16 + m) * LDK + quad * 8]);
                    lacc[0] = __builtin_amdgcn_mfma_f32_16x16x32_bf16(ap0, bones, lacc[0], 0, 0, 0);
                    lacc[1] = __builtin_amdgcn_mfma_f32_16x16x32_bf16(ap1, bones, lacc[1], 0, 0, 0);
                    #pragma unroll
                    for (int nt = 0; nt < 4; ++nt) {
                        const int dr = nt * 16 + m;
                        const int vc = (c2 * 8 + (half << 2) + quad) ^ m;
                        const bf16x8 bv = *(const bf16x8*)(&Vt[dr * 128 + vc * 8]);
                        zacc[0][nt] = __builtin_amdgcn_mfma_f32_16x16x32_bf16(ap0, bv, zacc[0][nt], 0, 0, 0);
                        zacc[1][nt] = __builtin_amdgcn_mfma_f32_16x16x32_bf16(ap1, bv, zacc[1][nt], 0, 0, 0);
                    }
                }
                __builtin_amdgcn_s_setprio(0);
            }
        }
    }

    // ---- combine tile b partials across wave pairs (w, w+4) via LDS ----
    __syncthreads();   // all compute done; K/V LDS reusable as f32 scratch
    if (w < 4) {
        float* zs = (float*)KsS + (size_t)w * 2048;   // 8192 f32 total
        float* ls = (float*)VtS + (size_t)w * 512;
        #pragma unroll
        for (int g = 0; g < 2; ++g) {
            #pragma unroll
            for (int nt = 0; nt < 4; ++nt)
                #pragma unroll
                for (int rg = 0; rg < 4; ++rg)
                    zs[((g * 4 + nt) * 4 + rg) * 64 + lane] = zacc[g][nt][rg];
            #pragma unroll
            for (int rg = 0; rg < 4; ++rg)
                ls[(g * 4 + rg) * 64 + lane] = lacc[g][rg];
        }
    }
    __syncthreads();
    if (w >= 4) {
        const int ww = w - 4;
        const float* zs = (const float*)KsS + (size_t)ww * 2048;
        const float* ls = (const float*)VtS + (size_t)ww * 512;
        #pragma unroll
        for (int g = 0; g < 2; ++g) {
            #pragma unroll
            for (int nt = 0; nt < 4; ++nt)
                #pragma unroll
                for (int rg = 0; rg < 4; ++rg)
                    zacc[g][nt][rg] += zs[((g * 4 + nt) * 4 + rg) * 64 + lane];
            #pragma unroll
            for (int rg = 0; rg < 4; ++rg)
                lacc[g][rg] += ls[(g * 4 + rg) * 64 + lane];

            float invl[4];
            #pragma unroll
            for (int rg = 0; rg < 4; ++rg)
                invl[rg] = 1.f / __shfl(lacc[g][rg], quad * 16);
            #pragma unroll
            for (int nt = 0; nt < 4; ++nt) {
                const int d = nt * 16 + m;
                #pragma unroll
                for (int rg = 0; rg < 4; ++rg) {
                    const int qrow = pb * 128 + g * 64 + wg * 16 + quad * 4 + rg;
                    z[(((size_t)b0 * SEQL + qrow) * NH + h) * DH + d] =
                        __float2bfloat16(zacc[g][nt][rg] * invl[rg]);
                }
            }
        }
    }
}

// ---------------------------------------------------------------------------
extern "C" void kernel_launch(void* const* d_in, const int* in_sizes, int n_in,
                              void* d_out, int out_size, void* d_ws, size_t ws_size,
                              hipStream_t stream)
{
    const float* x  = (const float*)d_in[0];
    const float* Wq = (const float*)d_in[1];
    const float* Wk = (const float*)d_in[2];
    const float* Wv = (const float*)d_in[3];
    const float* Wo = (const float*)d_in[4];
    const float* bq = (const float*)d_in[5];
    const float* bk = (const float*)d_in[6];
    const float* bv = (const float*)d_in[7];
    const float* bo = (const float*)d_in[8];
    float* out = (float*)d_out;

    const size_t TOK = (size_t)BATCH * SEQL;             // 4096
    const size_t QKV = TOK * DM;                         // 4M elems
    bf16* xb  = (bf16*)d_ws;                             // 4M
    bf16* Wt  = xb + QKV;                                // 4 x 1M
    bf16* qkv = Wt + 4 * (size_t)DM * DM;                // 3 x 4M
    bf16* zb  = qkv + 3 * QKV;                           // 4M   (48 MB total)

    prep_kernel<<<dim3(16, 16, 5), 256, 0, stream>>>(x, Wq, Wk, Wv, Wo, Wt, xb);
    qkv_gemm<<<dim3(8, 32, 3), 256, 0, stream>>>(xb, Wt, bq, bk, bv, qkv);
    attn_kernel<<<dim3(BATCH * NH, 8), 512, 0, stream>>>(
        qkv, qkv + QKV, qkv + 2 * QKV, zb);
    oproj_gemm<<<dim3(16, 32), 256, 0, stream>>>(zb, Wt + 3 * (size_t)DM * DM, bo, out);
}